// Round 3
// baseline (28479.382 us; speedup 1.0000x reference)
//
#include <hip/hip_runtime.h>
#include <hip/hip_bf16.h>
#include <stdint.h>

#define SEQ   512
#define BATCH 128
#define DIM   1024
#define BD    (BATCH * DIM)
#define NBLK  256
#define NGRP  8
#define GRPSZ (NBLK / NGRP)
#define LDS_BYTES 131072

typedef __bf16 bf16x8 __attribute__((ext_vector_type(8)));
typedef float  f32x4  __attribute__((ext_vector_type(4)));

__device__ __forceinline__ float sigf(float x) { return 1.0f / (1.0f + __expf(-x)); }

__device__ __forceinline__ bf16x8 pack_f32(float4 a, float4 b) {
    bf16x8 r;
    r[0] = (__bf16)a.x; r[1] = (__bf16)a.y; r[2] = (__bf16)a.z; r[3] = (__bf16)a.w;
    r[4] = (__bf16)b.x; r[5] = (__bf16)b.y; r[6] = (__bf16)b.z; r[7] = (__bf16)b.w;
    return r;
}
__device__ __forceinline__ bf16x8 pack_u64(unsigned long long a, unsigned long long b) {
    uint4 u = make_uint4((unsigned)a, (unsigned)(a >> 32), (unsigned)b, (unsigned)(b >> 32));
    return __builtin_bit_cast(bf16x8, u);
}
// Cross-XCD-coherent 8B load / 2B store (per-XCD L2 not coherent; all mutable
// cross-block state goes through agent-scope atomics -> MALL).
__device__ __forceinline__ unsigned long long ld_dev_u64(const __hip_bfloat16* p) {
    return __hip_atomic_load((const unsigned long long*)p, __ATOMIC_RELAXED,
                             __HIP_MEMORY_SCOPE_AGENT);
}
__device__ __forceinline__ void st_dev_bf16(__hip_bfloat16* p, float v) {
    unsigned short u = __builtin_bit_cast(unsigned short, (__bf16)v);
    __hip_atomic_store((unsigned short*)p, u, __ATOMIC_RELAXED, __HIP_MEMORY_SCOPE_AGENT);
}

// Hierarchical sense-reversing grid barrier.
// Layout (dwords, 64B line spacing): arrive[g]=sc[g*16], top=sc[128],
// gen[g]=sc[256+g*16]. Each arrival line sees 32 RMWs; each gen line is
// polled by only 32 blocks -> no single-line poll storm (Round-2 lesson:
// the flat 256-way barrier cost ~25us/phase under poll contention).
__device__ __forceinline__ void gsync(unsigned* sc, int bid) {
    __syncthreads();
    if (threadIdx.x == 0) {
        const int g = bid & (NGRP - 1);
        unsigned* ga = sc + g * 16;
        unsigned* gg = sc + 256 + g * 16;
        unsigned gen = __hip_atomic_load(gg, __ATOMIC_RELAXED, __HIP_MEMORY_SCOPE_AGENT);
        if (__hip_atomic_fetch_add(ga, 1u, __ATOMIC_ACQ_REL, __HIP_MEMORY_SCOPE_AGENT)
            == GRPSZ - 1) {
            __hip_atomic_store(ga, 0u, __ATOMIC_RELAXED, __HIP_MEMORY_SCOPE_AGENT);
            if (__hip_atomic_fetch_add(sc + 128, 1u, __ATOMIC_ACQ_REL,
                                       __HIP_MEMORY_SCOPE_AGENT) == NGRP - 1) {
                __hip_atomic_store(sc + 128, 0u, __ATOMIC_RELAXED, __HIP_MEMORY_SCOPE_AGENT);
#pragma unroll
                for (int i = 0; i < NGRP; ++i)
                    __hip_atomic_store(sc + 256 + i * 16, gen + 1u, __ATOMIC_RELEASE,
                                       __HIP_MEMORY_SCOPE_AGENT);
            } else {
                while (__hip_atomic_load(gg, __ATOMIC_ACQUIRE, __HIP_MEMORY_SCOPE_AGENT) == gen)
                    __builtin_amdgcn_s_sleep(4);
            }
        } else {
            while (__hip_atomic_load(gg, __ATOMIC_ACQUIRE, __HIP_MEMORY_SCOPE_AGENT) == gen)
                __builtin_amdgcn_s_sleep(4);
        }
    }
    __syncthreads();
}

// All 16 A-fragment loads issued up-front: one MALL latency exposure per GEMM.
__device__ __forceinline__ void load_h_frags(bf16x8 (&afr)[2][8],
    const __hip_bfloat16* Ab, size_t aoff0, size_t aoff1)
{
#pragma unroll
    for (int kc = 0; kc < 8; ++kc) {
        afr[0][kc] = pack_u64(ld_dev_u64(Ab + aoff0 + kc * 32),
                              ld_dev_u64(Ab + aoff0 + kc * 32 + 4));
        afr[1][kc] = pack_u64(ld_dev_u64(Ab + aoff1 + kc * 32),
                              ld_dev_u64(Ab + aoff1 + kc * 32 + 4));
    }
}
// emb is read-only during the kernel -> plain cacheable loads (L2-shared).
__device__ __forceinline__ void load_emb_frags(bf16x8 (&afr)[2][8],
    const float* e0, const float* e1)
{
#pragma unroll
    for (int kc = 0; kc < 8; ++kc) {
        afr[0][kc] = pack_f32(*(const float4*)(e0 + kc * 32),
                              *(const float4*)(e0 + kc * 32 + 4));
        afr[1][kc] = pack_f32(*(const float4*)(e1 + kc * 32),
                              *(const float4*)(e1 + kc * 32 + 4));
    }
}

__device__ __forceinline__ void mfma_all(const bf16x8 (&afr)[2][8],
    const bf16x8 (&breg)[4][8], f32x4 (&acc)[2][4])
{
#pragma unroll
    for (int kc = 0; kc < 8; ++kc)
#pragma unroll
        for (int mt = 0; mt < 2; ++mt)
#pragma unroll
            for (int nt = 0; nt < 4; ++nt)
                acc[mt][nt] = __builtin_amdgcn_mfma_f32_16x16x32_bf16(
                    afr[mt][kc], breg[nt][kc], acc[mt][nt], 0, 0, 0);
}

// Partials part[w][n=64][m=32] f32; m-index XOR-swizzled by (n>>2)&7 so the
// b128 writes stay 16B-aligned and the epilogue's scalar reads hit 32
// distinct banks (2 lanes/bank = free) instead of 8 (Round-2: 9.4e8 confl).
__device__ __forceinline__ void write_part(float* part, const f32x4 (&acc)[2][4],
    int w, int quad, int l16)
{
#pragma unroll
    for (int mt = 0; mt < 2; ++mt)
#pragma unroll
        for (int nt = 0; nt < 4; ++nt) {
            int n  = nt * 16 + l16;
            int dw = w * 2048 + n * 32 + ((mt * 16 + quad * 4) ^ (((n >> 2) & 7) << 2));
            *(f32x4*)(part + dw) = acc[mt][nt];
        }
}
__device__ __forceinline__ void read_part(const float* part, int rr, int jj, float (&g4)[4])
{
    g4[0] = g4[1] = g4[2] = g4[3] = 0.f;
    const int msw = rr ^ ((jj & 7) << 2);   // (n>>2)&7 == jj&7 for n = jj*4+g
#pragma unroll
    for (int wv = 0; wv < 8; ++wv)
#pragma unroll
        for (int g = 0; g < 4; ++g)
            g4[g] += part[wv * 2048 + (jj * 4 + g) * 32 + msw];
}

// Block = 32 batch rows x 16 hidden cols. Wave (s,kq). Weights persistent in
// 128 regs/lane. Per phase: cell2(t-1) GEMM -> issue cell1 loads -> ONE
// syncthreads (vmcnt drain does double duty) -> epi2 -> cell1 GEMM -> ONE
// syncthreads -> epi1 -> hierarchical gsync. Partials in separate LDS halves.
__global__ __launch_bounds__(512, 2) void lstm_persist(
    const int* __restrict__ x, const float* __restrict__ emb,
    const float* __restrict__ Wih, const float* __restrict__ Whh,
    const float* __restrict__ bih, const float* __restrict__ bhh,
    const float* __restrict__ h0, const float* __restrict__ c0,
    const float* __restrict__ h02, const float* __restrict__ c02,
    __hip_bfloat16* __restrict__ hbase, unsigned* __restrict__ sync,
    float* __restrict__ out)
{
    extern __shared__ float lds[];          // 128 KB
    float* partA = lds;                     // cell2 partials
    float* partB = lds + 16384;             // cell1 partials

    const int tid  = threadIdx.x;
    const int w    = tid >> 6;
    const int lane = tid & 63;
    const int quad = lane >> 4;
    const int l16  = lane & 15;
    const int s    = w & 1;
    const int kq   = w >> 1;
    const int cg   = blockIdx.x & 63;
    const int mqh  = blockIdx.x >> 6;
    const int R0   = mqh * 32;
    const int J0   = cg * 16;
    const int rr   = tid >> 4;              // epilogue local row 0..31
    const int jj   = tid & 15;              // epilogue local col
    const int col  = J0 + jj;
    const int grow = R0 + rr;
    const size_t off = (size_t)grow * DIM + col;

    const int arow0 = R0 + l16;
    const int arow1 = R0 + 16 + l16;
    const int kb    = kq * 256 + quad * 8;
    const size_t aoff0 = (size_t)arow0 * DIM + kb;
    const size_t aoff1 = (size_t)arow1 * DIM + kb;

    __hip_bfloat16* hbf0  = hbase;
    __hip_bfloat16* hbf1  = hbase + BD;
    __hip_bfloat16* h1bf0 = hbase + 2 * BD;
    __hip_bfloat16* h1bf1 = hbase + 3 * BD;
    __hip_bfloat16* h2bf0 = hbase + 4 * BD;
    __hip_bfloat16* h2bf1 = hbase + 5 * BD;

    // ---- persistent weight fragments: W[n=j*4+g][k] ----
    bf16x8 breg[4][8];
    {
        const float* Wm = s ? Whh : Wih;
#pragma unroll
        for (int nt = 0; nt < 4; ++nt) {
            int n = nt * 16 + l16;
            const float* wp = Wm + (size_t)((n & 3) * DIM + J0 + (n >> 2)) * DIM + kb;
#pragma unroll
            for (int kc = 0; kc < 8; ++kc)
                breg[nt][kc] = pack_f32(*(const float4*)(wp + kc * 32),
                                        *(const float4*)(wp + kc * 32 + 4));
        }
    }

    // ---- persistent per-thread cell state ----
    float hc  = h0[col],  cc1 = c0[col];
    float hp  = hc,       cp  = cc1;        // layer-1 pre-state (cell2 pad fallback)
    float h2f = h02[col], c2f = c02[col];
    float bias[4];
#pragma unroll
    for (int g = 0; g < 4; ++g) bias[g] = bih[g * DIM + col] + bhh[g * DIM + col];

    // token registers, preloaded one phase ahead (x is read-only, L2-hot)
    int ta0 = x[arow0], ta1 = x[arow1];     // gather rows for cell1 A-frags (s==0)
    int gxc = x[grow];                       // pad-mask token for MY row, step t
    int gxp = 0;                             // step t-1 (set at end of phase 0)

    st_dev_bf16(hbf1 + off, hc);            // parity 1 = state before step 0
    st_dev_bf16(h2bf1 + off, h2f);
    gsync(sync, blockIdx.x);

#pragma unroll 1
    for (int t = 0; t <= SEQ; ++t) {
        bf16x8 afr1[2][8];
        if (t >= 1) {
            // ---- cell2(t-1) GEMM: s=0 -> h1(t-1)@Wih, s=1 -> h2(t-2)@Whh ----
            const __hip_bfloat16* Ab = (s == 0)
                ? (((t - 1) & 1) ? h1bf1 : h1bf0)
                : ((t & 1) ? h2bf1 : h2bf0);
            bf16x8 afr2[2][8];
            load_h_frags(afr2, Ab, aoff0, aoff1);
            f32x4 acc[2][4];
#pragma unroll
            for (int mt = 0; mt < 2; ++mt)
#pragma unroll
                for (int nt = 0; nt < 4; ++nt) acc[mt][nt] = (f32x4)(0.f);
            mfma_all(afr2, breg, acc);
            // issue cell1 operand loads now (afr2 regs dead): the mandatory
            // vmcnt drain at the next __syncthreads covers this latency.
            if (t < SEQ) {
                if (s == 0)
                    load_emb_frags(afr1, emb + (size_t)ta0 * DIM + kb,
                                         emb + (size_t)ta1 * DIM + kb);
                else
                    load_h_frags(afr1, ((t + 1) & 1) ? hbf1 : hbf0, aoff0, aoff1);
            }
            write_part(partA, acc, w, quad, l16);
        } else {
            if (s == 0)
                load_emb_frags(afr1, emb + (size_t)ta0 * DIM + kb,
                                     emb + (size_t)ta1 * DIM + kb);
            else
                load_h_frags(afr1, hbf1, aoff0, aoff1);
        }
        __syncthreads();
        if (t >= 1) {
            // ---- epilogue cell2(t-1) ----
            float g4[4]; read_part(partA, rr, jj, g4);
            float gi = g4[0] + bias[0], gf = g4[1] + bias[1];
            float gg = g4[2] + bias[2], go = g4[3] + bias[3];
            float cn = sigf(gf) * c2f + sigf(gi) * tanhf(gg);
            float hn = sigf(go) * tanhf(cn);
            bool pad = (gxp == 0);
            h2f = pad ? hp : hn;            // pad fallback = layer-1 PRE-state
            c2f = pad ? cp : cn;
            st_dev_bf16((((t - 1) & 1) ? h2bf1 : h2bf0) + off, h2f);
        }
        if (t < SEQ) {
            // ---- cell1(t) GEMM (operands already resident) ----
            f32x4 acc[2][4];
#pragma unroll
            for (int mt = 0; mt < 2; ++mt)
#pragma unroll
                for (int nt = 0; nt < 4; ++nt) acc[mt][nt] = (f32x4)(0.f);
            mfma_all(afr1, breg, acc);
            write_part(partB, acc, w, quad, l16);
            __syncthreads();
            // ---- epilogue cell1(t) ----
            float g4[4]; read_part(partB, rr, jj, g4);
            float gi = g4[0] + bias[0], gf = g4[1] + bias[1];
            float gg = g4[2] + bias[2], go = g4[3] + bias[3];
            float cn = sigf(gf) * cc1 + sigf(gi) * tanhf(gg);
            float hn = sigf(go) * tanhf(cn);
            bool pad = (gxc == 0);
            float hm = pad ? hc : hn;
            float cm = pad ? cc1 : cn;
            st_dev_bf16(((t & 1) ? h1bf1 : h1bf0) + off, hn);   // UNMASKED -> layer2
            st_dev_bf16(((t & 1) ? hbf1 : hbf0) + off, hm);     // masked -> next cell1
            hp = hc; cp = cc1; hc = hm; cc1 = cm;
            gxp = gxc;
            int tn = (t + 1 < SEQ) ? t + 1 : t;                 // preload next tokens
            gxc = x[tn * BATCH + grow];
            ta0 = x[tn * BATCH + arow0];
            ta1 = x[tn * BATCH + arow1];
            gsync(sync, blockIdx.x);
        }
    }

    out[0 * BD + off] = hc;
    out[1 * BD + off] = cc1;
    out[2 * BD + off] = h2f;
    out[3 * BD + off] = c2f;
}

__global__ void zero_sync_k(unsigned* sc) {
    sc[threadIdx.x] = 0u;
}

extern "C" void kernel_launch(void* const* d_in, const int* in_sizes, int n_in,
                              void* d_out, int out_size, void* d_ws, size_t ws_size,
                              hipStream_t stream) {
    (void)in_sizes; (void)n_in; (void)out_size; (void)ws_size;
    const int*   x    = (const int*)d_in[0];
    const float* emb  = (const float*)d_in[1];
    const float* Wih  = (const float*)d_in[2];
    const float* Whh  = (const float*)d_in[3];
    const float* bih  = (const float*)d_in[4];
    const float* bhh  = (const float*)d_in[5];
    const float* h0   = (const float*)d_in[6];
    const float* c0   = (const float*)d_in[7];
    const float* h02  = (const float*)d_in[8];
    const float* c02  = (const float*)d_in[9];

    unsigned* sync = (unsigned*)d_ws;
    __hip_bfloat16* hbase = (__hip_bfloat16*)((char*)d_ws + 4096);
    float* outp = (float*)d_out;

    static int attr_done = 0;
    if (!attr_done) {
        (void)hipFuncSetAttribute((const void*)lstm_persist,
                                  hipFuncAttributeMaxDynamicSharedMemorySize, LDS_BYTES);
        attr_done = 1;
    }

    zero_sync_k<<<1, 512, 0, stream>>>(sync);

    void* args[] = { (void*)&x, (void*)&emb, (void*)&Wih, (void*)&Whh,
                     (void*)&bih, (void*)&bhh, (void*)&h0, (void*)&c0,
                     (void*)&h02, (void*)&c02, (void*)&hbase, (void*)&sync,
                     (void*)&outp };
    hipError_t e = hipLaunchCooperativeKernel((const void*)lstm_persist,
                                              dim3(NBLK), dim3(512), args,
                                              (unsigned)LDS_BYTES, stream);
    if (e != hipSuccess) {
        // Fallback: plain launch. 128 KB LDS -> 1 block/CU, grid == CU count,
        // all 256 blocks co-resident; hand-rolled barrier remains safe.
        lstm_persist<<<NBLK, 512, LDS_BYTES, stream>>>(
            x, emb, Wih, Whh, bih, bhh, h0, c0, h02, c02, hbase, sync, outp);
    }
}

// Round 4
// 14060.980 us; speedup vs baseline: 2.0254x; 2.0254x over previous
//
#include <hip/hip_runtime.h>
#include <hip/hip_bf16.h>
#include <stdint.h>

#define SEQ   512
#define BATCH 128
#define DIM   1024
#define BD    (BATCH * DIM)
#define NBLK  256
#define NGRP  8
#define GRPSZ (NBLK / NGRP)
#define LDS_BYTES 131072

typedef __bf16 bf16x8 __attribute__((ext_vector_type(8)));
typedef float  f32x4  __attribute__((ext_vector_type(4)));

__device__ __forceinline__ float sigf(float x) { return 1.0f / (1.0f + __expf(-x)); }

__device__ __forceinline__ bf16x8 pack_f32(float4 a, float4 b) {
    bf16x8 r;
    r[0] = (__bf16)a.x; r[1] = (__bf16)a.y; r[2] = (__bf16)a.z; r[3] = (__bf16)a.w;
    r[4] = (__bf16)b.x; r[5] = (__bf16)b.y; r[6] = (__bf16)b.z; r[7] = (__bf16)b.w;
    return r;
}
__device__ __forceinline__ bf16x8 pack_u64(unsigned long long a, unsigned long long b) {
    uint4 u = make_uint4((unsigned)a, (unsigned)(a >> 32), (unsigned)b, (unsigned)(b >> 32));
    return __builtin_bit_cast(bf16x8, u);
}
// RELAXED agent-scope ops: routed to the coherence point (MALL) via sc bits,
// with NO cache-maintenance instructions (acquire/release at agent scope
// emit buffer_inv / buffer_wbl2 on gfx950 -> the R1-R3 L2-thrash storm).
__device__ __forceinline__ unsigned long long ld_dev_u64(const __hip_bfloat16* p) {
    return __hip_atomic_load((const unsigned long long*)p, __ATOMIC_RELAXED,
                             __HIP_MEMORY_SCOPE_AGENT);
}
__device__ __forceinline__ void st_dev_bf16(__hip_bfloat16* p, float v) {
    unsigned short u = __builtin_bit_cast(unsigned short, (__bf16)v);
    __hip_atomic_store((unsigned short*)p, u, __ATOMIC_RELAXED, __HIP_MEMORY_SCOPE_AGENT);
}
__device__ __forceinline__ unsigned ld_sc(const unsigned* p) {
    return __hip_atomic_load(p, __ATOMIC_RELAXED, __HIP_MEMORY_SCOPE_AGENT);
}
__device__ __forceinline__ void st_sc(unsigned* p, unsigned v) {
    __hip_atomic_store(p, v, __ATOMIC_RELAXED, __HIP_MEMORY_SCOPE_AGENT);
}
__device__ __forceinline__ unsigned rmw_sc(unsigned* p) {
    return __hip_atomic_fetch_add(p, 1u, __ATOMIC_RELAXED, __HIP_MEMORY_SCOPE_AGENT);
}

// Hierarchical ALL-RELAXED grid barrier with parity-indexed counters.
// Layout (dword idx, 64B line spacing): arrive[p][g] = sc[(p*8+g)*16],
// top[p] = sc[(16+p)*16], gen[g] = sc[(24+g)*16].
// Correctness: (a) data visibility -- all cross-block data uses relaxed
// agent ops that hit MALL; __syncthreads' vmcnt drain retires them before
// the leader's arrival RMW reaches MALL. (b) reset safety -- a parity-p
// counter is next used two phases later, which requires the whole grid to
// pass the intervening release; relaxed resets have an entire phase to land.
__device__ __forceinline__ void gsync(unsigned* sc, int bid) {
    __syncthreads();
    if (threadIdx.x == 0) {
        const int g = bid & (NGRP - 1);
        unsigned* genl = sc + (24 + g) * 16;
        unsigned gen = ld_sc(genl);
        const unsigned p = gen & 1u;
        unsigned* ga = sc + (p * 8 + g) * 16;
        if (rmw_sc(ga) == GRPSZ - 1) {
            st_sc(ga, 0u);
            unsigned* tp = sc + (16 + p) * 16;
            if (rmw_sc(tp) == NGRP - 1) {
                st_sc(tp, 0u);
#pragma unroll
                for (int i = 0; i < NGRP; ++i)
                    st_sc(sc + (24 + i) * 16, gen + 1u);
            } else {
                while (ld_sc(genl) == gen) __builtin_amdgcn_s_sleep(1);
            }
        } else {
            while (ld_sc(genl) == gen) __builtin_amdgcn_s_sleep(1);
        }
    }
    __syncthreads();
}

// All 16 A-fragment loads issued up-front: one MALL latency exposure per GEMM.
__device__ __forceinline__ void load_h_frags(bf16x8 (&afr)[2][8],
    const __hip_bfloat16* Ab, size_t aoff0, size_t aoff1)
{
#pragma unroll
    for (int kc = 0; kc < 8; ++kc) {
        afr[0][kc] = pack_u64(ld_dev_u64(Ab + aoff0 + kc * 32),
                              ld_dev_u64(Ab + aoff0 + kc * 32 + 4));
        afr[1][kc] = pack_u64(ld_dev_u64(Ab + aoff1 + kc * 32),
                              ld_dev_u64(Ab + aoff1 + kc * 32 + 4));
    }
}
// emb/x are read-only -> plain cacheable loads; with the invalidate storm
// gone they stay L2/MALL-resident.
__device__ __forceinline__ void load_emb_frags(bf16x8 (&afr)[2][8],
    const float* e0, const float* e1)
{
#pragma unroll
    for (int kc = 0; kc < 8; ++kc) {
        afr[0][kc] = pack_f32(*(const float4*)(e0 + kc * 32),
                              *(const float4*)(e0 + kc * 32 + 4));
        afr[1][kc] = pack_f32(*(const float4*)(e1 + kc * 32),
                              *(const float4*)(e1 + kc * 32 + 4));
    }
}

__device__ __forceinline__ void mfma_all(const bf16x8 (&afr)[2][8],
    const bf16x8 (&breg)[4][8], f32x4 (&acc)[2][4])
{
#pragma unroll
    for (int kc = 0; kc < 8; ++kc)
#pragma unroll
        for (int mt = 0; mt < 2; ++mt)
#pragma unroll
            for (int nt = 0; nt < 4; ++nt)
                acc[mt][nt] = __builtin_amdgcn_mfma_f32_16x16x32_bf16(
                    afr[mt][kc], breg[nt][kc], acc[mt][nt], 0, 0, 0);
}

// Partials part[w][n=64][m=32] f32, m-index XOR-swizzled by
// a(n) = ((n>>2)&7) ^ ((n&3)<<1)  (4-dword granular -> b128 stays aligned).
// Hand-checked: b128 writes spread uniformly over all 8 bank-groups
// (r3's v2 hit only 4 -> 4-way conflict); scalar epilogue reads cover all
// 32 banks at 2 lanes/bank (free).
__device__ __forceinline__ void write_part(float* part, const f32x4 (&acc)[2][4],
    int w, int quad, int l16)
{
#pragma unroll
    for (int mt = 0; mt < 2; ++mt)
#pragma unroll
        for (int nt = 0; nt < 4; ++nt) {
            int n  = nt * 16 + l16;
            int a  = ((n >> 2) & 7) ^ ((n & 3) << 1);
            int dw = w * 2048 + n * 32 + ((mt * 16 + quad * 4) ^ (a << 2));
            *(f32x4*)(part + dw) = acc[mt][nt];
        }
}
__device__ __forceinline__ void read_part(const float* part, int rr, int jj, float (&g4)[4])
{
    g4[0] = g4[1] = g4[2] = g4[3] = 0.f;
#pragma unroll
    for (int wv = 0; wv < 8; ++wv)
#pragma unroll
        for (int g = 0; g < 4; ++g) {
            int a = ((jj & 7) ^ (g << 1));          // == a(jj*4+g)
            g4[g] += part[wv * 2048 + (jj * 4 + g) * 32 + (rr ^ (a << 2))];
        }
}

// Block = 32 batch rows x 16 hidden cols. Wave (s,kq). Weights persistent in
// 128 regs/lane. Per phase: cell2(t-1) GEMM -> issue cell1 loads -> ONE
// syncthreads (vmcnt drain does double duty) -> epi2 -> cell1 GEMM -> ONE
// syncthreads -> epi1 -> relaxed hierarchical gsync.
__global__ __launch_bounds__(512, 2) void lstm_persist(
    const int* __restrict__ x, const float* __restrict__ emb,
    const float* __restrict__ Wih, const float* __restrict__ Whh,
    const float* __restrict__ bih, const float* __restrict__ bhh,
    const float* __restrict__ h0, const float* __restrict__ c0,
    const float* __restrict__ h02, const float* __restrict__ c02,
    __hip_bfloat16* __restrict__ hbase, unsigned* __restrict__ sync,
    float* __restrict__ out)
{
    extern __shared__ float lds[];          // 128 KB
    float* partA = lds;                     // cell2 partials
    float* partB = lds + 16384;             // cell1 partials

    const int tid  = threadIdx.x;
    const int w    = tid >> 6;
    const int lane = tid & 63;
    const int quad = lane >> 4;
    const int l16  = lane & 15;
    const int s    = w & 1;
    const int kq   = w >> 1;
    const int cg   = blockIdx.x & 63;
    const int mqh  = blockIdx.x >> 6;
    const int R0   = mqh * 32;
    const int J0   = cg * 16;
    const int rr   = tid >> 4;              // epilogue local row 0..31
    const int jj   = tid & 15;              // epilogue local col
    const int col  = J0 + jj;
    const int grow = R0 + rr;
    const size_t off = (size_t)grow * DIM + col;

    const int arow0 = R0 + l16;
    const int arow1 = R0 + 16 + l16;
    const int kb    = kq * 256 + quad * 8;
    const size_t aoff0 = (size_t)arow0 * DIM + kb;
    const size_t aoff1 = (size_t)arow1 * DIM + kb;

    __hip_bfloat16* hbf0  = hbase;
    __hip_bfloat16* hbf1  = hbase + BD;
    __hip_bfloat16* h1bf0 = hbase + 2 * BD;
    __hip_bfloat16* h1bf1 = hbase + 3 * BD;
    __hip_bfloat16* h2bf0 = hbase + 4 * BD;
    __hip_bfloat16* h2bf1 = hbase + 5 * BD;

    // ---- persistent weight fragments: W[n=j*4+g][k] ----
    bf16x8 breg[4][8];
    {
        const float* Wm = s ? Whh : Wih;
#pragma unroll
        for (int nt = 0; nt < 4; ++nt) {
            int n = nt * 16 + l16;
            const float* wp = Wm + (size_t)((n & 3) * DIM + J0 + (n >> 2)) * DIM + kb;
#pragma unroll
            for (int kc = 0; kc < 8; ++kc)
                breg[nt][kc] = pack_f32(*(const float4*)(wp + kc * 32),
                                        *(const float4*)(wp + kc * 32 + 4));
        }
    }

    // ---- persistent per-thread cell state ----
    float hc  = h0[col],  cc1 = c0[col];
    float hp  = hc,       cp  = cc1;        // layer-1 pre-state (cell2 pad fallback)
    float h2f = h02[col], c2f = c02[col];
    float bias[4];
#pragma unroll
    for (int g = 0; g < 4; ++g) bias[g] = bih[g * DIM + col] + bhh[g * DIM + col];

    // token registers, preloaded one phase ahead (x is read-only, L2-hot)
    int ta0 = x[arow0], ta1 = x[arow1];     // gather rows for cell1 A-frags (s==0)
    int gxc = x[grow];                      // pad-mask token for MY row, step t
    int gxp = 0;                            // step t-1 (set at end of phase 0)

    st_dev_bf16(hbf1 + off, hc);            // parity 1 = state before step 0
    st_dev_bf16(h2bf1 + off, h2f);
    gsync(sync, blockIdx.x);

#pragma unroll 1
    for (int t = 0; t <= SEQ; ++t) {
        bf16x8 afr1[2][8];
        if (t >= 1) {
            // ---- cell2(t-1) GEMM: s=0 -> h1(t-1)@Wih, s=1 -> h2(t-2)@Whh ----
            const __hip_bfloat16* Ab = (s == 0)
                ? (((t - 1) & 1) ? h1bf1 : h1bf0)
                : ((t & 1) ? h2bf1 : h2bf0);
            bf16x8 afr2[2][8];
            load_h_frags(afr2, Ab, aoff0, aoff1);
            f32x4 acc[2][4];
#pragma unroll
            for (int mt = 0; mt < 2; ++mt)
#pragma unroll
                for (int nt = 0; nt < 4; ++nt) acc[mt][nt] = (f32x4)(0.f);
            mfma_all(afr2, breg, acc);
            // issue cell1 operand loads now (afr2 regs dead): the mandatory
            // vmcnt drain at the next __syncthreads covers this latency.
            if (t < SEQ) {
                if (s == 0)
                    load_emb_frags(afr1, emb + (size_t)ta0 * DIM + kb,
                                         emb + (size_t)ta1 * DIM + kb);
                else
                    load_h_frags(afr1, ((t + 1) & 1) ? hbf1 : hbf0, aoff0, aoff1);
            }
            write_part(partA, acc, w, quad, l16);
        } else {
            if (s == 0)
                load_emb_frags(afr1, emb + (size_t)ta0 * DIM + kb,
                                     emb + (size_t)ta1 * DIM + kb);
            else
                load_h_frags(afr1, hbf1, aoff0, aoff1);
        }
        __syncthreads();
        if (t >= 1) {
            // ---- epilogue cell2(t-1) ----
            float g4[4]; read_part(partA, rr, jj, g4);
            float gi = g4[0] + bias[0], gf = g4[1] + bias[1];
            float gg = g4[2] + bias[2], go = g4[3] + bias[3];
            float cn = sigf(gf) * c2f + sigf(gi) * tanhf(gg);
            float hn = sigf(go) * tanhf(cn);
            bool pad = (gxp == 0);
            h2f = pad ? hp : hn;            // pad fallback = layer-1 PRE-state
            c2f = pad ? cp : cn;
            st_dev_bf16((((t - 1) & 1) ? h2bf1 : h2bf0) + off, h2f);
        }
        if (t < SEQ) {
            // ---- cell1(t) GEMM (operands already resident) ----
            f32x4 acc[2][4];
#pragma unroll
            for (int mt = 0; mt < 2; ++mt)
#pragma unroll
                for (int nt = 0; nt < 4; ++nt) acc[mt][nt] = (f32x4)(0.f);
            mfma_all(afr1, breg, acc);
            write_part(partB, acc, w, quad, l16);
            __syncthreads();
            // ---- epilogue cell1(t) ----
            float g4[4]; read_part(partB, rr, jj, g4);
            float gi = g4[0] + bias[0], gf = g4[1] + bias[1];
            float gg = g4[2] + bias[2], go = g4[3] + bias[3];
            float cn = sigf(gf) * cc1 + sigf(gi) * tanhf(gg);
            float hn = sigf(go) * tanhf(cn);
            bool pad = (gxc == 0);
            float hm = pad ? hc : hn;
            float cm = pad ? cc1 : cn;
            st_dev_bf16(((t & 1) ? h1bf1 : h1bf0) + off, hn);   // UNMASKED -> layer2
            st_dev_bf16(((t & 1) ? hbf1 : hbf0) + off, hm);     // masked -> next cell1
            hp = hc; cp = cc1; hc = hm; cc1 = cm;
            gxp = gxc;
            int tn = (t + 1 < SEQ) ? t + 1 : t;                 // preload next tokens
            gxc = x[tn * BATCH + grow];
            ta0 = x[tn * BATCH + arow0];
            ta1 = x[tn * BATCH + arow1];
            gsync(sync, blockIdx.x);
        }
    }

    out[0 * BD + off] = hc;
    out[1 * BD + off] = cc1;
    out[2 * BD + off] = h2f;
    out[3 * BD + off] = c2f;
}

__global__ void zero_sync_k(unsigned* sc) {
    sc[threadIdx.x] = 0u;   // covers dword indices 0..511 (max used: 496)
}

extern "C" void kernel_launch(void* const* d_in, const int* in_sizes, int n_in,
                              void* d_out, int out_size, void* d_ws, size_t ws_size,
                              hipStream_t stream) {
    (void)in_sizes; (void)n_in; (void)out_size; (void)ws_size;
    const int*   x    = (const int*)d_in[0];
    const float* emb  = (const float*)d_in[1];
    const float* Wih  = (const float*)d_in[2];
    const float* Whh  = (const float*)d_in[3];
    const float* bih  = (const float*)d_in[4];
    const float* bhh  = (const float*)d_in[5];
    const float* h0   = (const float*)d_in[6];
    const float* c0   = (const float*)d_in[7];
    const float* h02  = (const float*)d_in[8];
    const float* c02  = (const float*)d_in[9];

    unsigned* sync = (unsigned*)d_ws;
    __hip_bfloat16* hbase = (__hip_bfloat16*)((char*)d_ws + 4096);
    float* outp = (float*)d_out;

    static int attr_done = 0;
    if (!attr_done) {
        (void)hipFuncSetAttribute((const void*)lstm_persist,
                                  hipFuncAttributeMaxDynamicSharedMemorySize, LDS_BYTES);
        attr_done = 1;
    }

    zero_sync_k<<<1, 512, 0, stream>>>(sync);

    void* args[] = { (void*)&x, (void*)&emb, (void*)&Wih, (void*)&Whh,
                     (void*)&bih, (void*)&bhh, (void*)&h0, (void*)&c0,
                     (void*)&h02, (void*)&c02, (void*)&hbase, (void*)&sync,
                     (void*)&outp };
    hipError_t e = hipLaunchCooperativeKernel((const void*)lstm_persist,
                                              dim3(NBLK), dim3(512), args,
                                              (unsigned)LDS_BYTES, stream);
    if (e != hipSuccess) {
        // Fallback: plain launch. 128 KB LDS -> 1 block/CU, grid == CU count,
        // all 256 blocks co-resident; hand-rolled barrier remains safe.
        lstm_persist<<<NBLK, 512, LDS_BYTES, stream>>>(
            x, emb, Wih, Whh, bih, bhh, h0, c0, h02, c02, hbase, sync, outp);
    }
}

// Round 5
// 11904.749 us; speedup vs baseline: 2.3923x; 1.1811x over previous
//
#include <hip/hip_runtime.h>
#include <hip/hip_bf16.h>
#include <stdint.h>

#define SEQ   512
#define BATCH 128
#define DIM   1024
#define BD    (BATCH * DIM)
#define NBLK  256
#define LDS_BYTES 131072

typedef __bf16 bf16x8 __attribute__((ext_vector_type(8)));
typedef float  f32x4  __attribute__((ext_vector_type(4)));

__device__ __forceinline__ float sigf(float x) { return 1.0f / (1.0f + __expf(-x)); }

__device__ __forceinline__ bf16x8 pack_f32(float4 a, float4 b) {
    bf16x8 r;
    r[0] = (__bf16)a.x; r[1] = (__bf16)a.y; r[2] = (__bf16)a.z; r[3] = (__bf16)a.w;
    r[4] = (__bf16)b.x; r[5] = (__bf16)b.y; r[6] = (__bf16)b.z; r[7] = (__bf16)b.w;
    return r;
}
// Plain cached 16B load of 8 bf16 (h-state: L2-cached, full TCC rate; the
// per-phase acquire fence in gsync provides cross-XCD visibility).
__device__ __forceinline__ bf16x8 ld_b16x8(const __hip_bfloat16* p) {
    uint4 u = *reinterpret_cast<const uint4*>(p);
    return __builtin_bit_cast(bf16x8, u);
}
// Writer side stays agent-scope relaxed (sc1 write-through to MALL): readers'
// invalidated L2s re-fetch from MALL and see it. No cache-maintenance insts.
__device__ __forceinline__ void st_dev_bf16(__hip_bfloat16* p, float v) {
    unsigned short u = __builtin_bit_cast(unsigned short, (__bf16)v);
    __hip_atomic_store((unsigned short*)p, u, __ATOMIC_RELAXED, __HIP_MEMORY_SCOPE_AGENT);
}
// 4 neighboring cols gathered by shuffle -> one 8B agent store (4x fewer
// fabric atomic ops than per-element 2B stores).
__device__ __forceinline__ void st_row8(__hip_bfloat16* p, float v, int jj) {
    float v1 = __shfl_down(v, 1);
    float v2 = __shfl_down(v, 2);
    float v3 = __shfl_down(v, 3);
    if ((jj & 3) == 0) {
        union { unsigned short s[4]; unsigned long long u; } q;
        q.s[0] = __builtin_bit_cast(unsigned short, (__bf16)v);
        q.s[1] = __builtin_bit_cast(unsigned short, (__bf16)v1);
        q.s[2] = __builtin_bit_cast(unsigned short, (__bf16)v2);
        q.s[3] = __builtin_bit_cast(unsigned short, (__bf16)v3);
        __hip_atomic_store((unsigned long long*)p, q.u, __ATOMIC_RELAXED,
                           __HIP_MEMORY_SCOPE_AGENT);
    }
}
__device__ __forceinline__ unsigned ld_sc(const unsigned* p) {
    return __hip_atomic_load(p, __ATOMIC_RELAXED, __HIP_MEMORY_SCOPE_AGENT);
}
__device__ __forceinline__ void st_sc(unsigned* p, unsigned v) {
    __hip_atomic_store(p, v, __ATOMIC_RELAXED, __HIP_MEMORY_SCOPE_AGENT);
}
__device__ __forceinline__ unsigned rmw_sc(unsigned* p) {
    return __hip_atomic_fetch_add(p, 1u, __ATOMIC_RELAXED, __HIP_MEMORY_SCOPE_AGENT);
}

// Per-row-group (64-block) hierarchical relaxed barrier + ONE acquire fence.
// Batch rows never interact: each row-group only exchanges h-columns among
// its own 64 col-blocks -> 4 independent barrier domains (scd = per-domain
// 4KB region). Structure per domain: 8 subgroups of 8 (parity-indexed
// counters, all relaxed -> no fence storm). The single acquire fence at the
// end invalidates this CU's L1 + XCD's L2 so this phase's PLAIN h-loads
// observe peer blocks' MALL-written state. Nothing dirty lives in L2
// (h-stores are write-through sc1), so the inv only costs clean re-fetches.
__device__ __forceinline__ void gsync(unsigned* scd, int cg) {
    __syncthreads();
    if (threadIdx.x == 0) {
        const int g = cg & 7;
        unsigned* genl = scd + (24 + g) * 16;
        unsigned gen = ld_sc(genl);
        const unsigned p = gen & 1u;
        unsigned* ga = scd + (p * 8 + g) * 16;
        if (rmw_sc(ga) == 7u) {
            st_sc(ga, 0u);
            unsigned* tp = scd + (16 + p) * 16;
            if (rmw_sc(tp) == 7u) {
                st_sc(tp, 0u);
#pragma unroll
                for (int i = 0; i < 8; ++i)
                    st_sc(scd + (24 + i) * 16, gen + 1u);
            } else {
                while (ld_sc(genl) == gen) __builtin_amdgcn_s_sleep(1);
            }
        } else {
            while (ld_sc(genl) == gen) __builtin_amdgcn_s_sleep(1);
        }
        __builtin_amdgcn_fence(__ATOMIC_ACQUIRE, "agent");   // L1+L2 inv, once
    }
    __syncthreads();
}

// All 16 A-fragment loads issued up-front: one latency exposure per GEMM.
__device__ __forceinline__ void load_h_frags(bf16x8 (&afr)[2][8],
    const __hip_bfloat16* Ab, size_t aoff0, size_t aoff1)
{
#pragma unroll
    for (int kc = 0; kc < 8; ++kc) {
        afr[0][kc] = ld_b16x8(Ab + aoff0 + kc * 32);
        afr[1][kc] = ld_b16x8(Ab + aoff1 + kc * 32);
    }
}
__device__ __forceinline__ void load_emb_frags(bf16x8 (&afr)[2][8],
    const float* e0, const float* e1)
{
#pragma unroll
    for (int kc = 0; kc < 8; ++kc) {
        afr[0][kc] = pack_f32(*(const float4*)(e0 + kc * 32),
                              *(const float4*)(e0 + kc * 32 + 4));
        afr[1][kc] = pack_f32(*(const float4*)(e1 + kc * 32),
                              *(const float4*)(e1 + kc * 32 + 4));
    }
}

__device__ __forceinline__ void mfma_all(const bf16x8 (&afr)[2][8],
    const bf16x8 (&breg)[4][8], f32x4 (&acc)[2][4])
{
#pragma unroll
    for (int kc = 0; kc < 8; ++kc)
#pragma unroll
        for (int mt = 0; mt < 2; ++mt)
#pragma unroll
            for (int nt = 0; nt < 4; ++nt)
                acc[mt][nt] = __builtin_amdgcn_mfma_f32_16x16x32_bf16(
                    afr[mt][kc], breg[nt][kc], acc[mt][nt], 0, 0, 0);
}

// Partials part[w][n=64][m=32] f32, m-index XOR-swizzled by
// a(n) = ((n>>2)&7) ^ ((n&3)<<1): b128 writes spread over all 8 bank-groups,
// scalar epilogue reads cover 32 banks at 2 lanes/bank (R4: conflicts 4x down).
__device__ __forceinline__ void write_part(float* part, const f32x4 (&acc)[2][4],
    int w, int quad, int l16)
{
#pragma unroll
    for (int mt = 0; mt < 2; ++mt)
#pragma unroll
        for (int nt = 0; nt < 4; ++nt) {
            int n  = nt * 16 + l16;
            int a  = ((n >> 2) & 7) ^ ((n & 3) << 1);
            int dw = w * 2048 + n * 32 + ((mt * 16 + quad * 4) ^ (a << 2));
            *(f32x4*)(part + dw) = acc[mt][nt];
        }
}
__device__ __forceinline__ void read_part(const float* part, int rr, int jj, float (&g4)[4])
{
    g4[0] = g4[1] = g4[2] = g4[3] = 0.f;
#pragma unroll
    for (int wv = 0; wv < 8; ++wv)
#pragma unroll
        for (int g = 0; g < 4; ++g) {
            int a = ((jj & 7) ^ (g << 1));          // == a(jj*4+g)
            g4[g] += part[wv * 2048 + (jj * 4 + g) * 32 + (rr ^ (a << 2))];
        }
}

// Block = 32 batch rows x 16 hidden cols. Wave (s,kq). Weights persistent in
// 128 regs/lane. Per phase: cell2(t-1) GEMM -> issue cell1 loads -> sync ->
// epi2 -> cell1 GEMM -> sync -> epi1 -> per-row-group gsync (+acquire inv).
__global__ __launch_bounds__(512, 2) void lstm_persist(
    const int* __restrict__ x, const float* __restrict__ emb,
    const float* __restrict__ Wih, const float* __restrict__ Whh,
    const float* __restrict__ bih, const float* __restrict__ bhh,
    const float* __restrict__ h0, const float* __restrict__ c0,
    const float* __restrict__ h02, const float* __restrict__ c02,
    __hip_bfloat16* __restrict__ hbase, unsigned* __restrict__ sync,
    float* __restrict__ out)
{
    extern __shared__ float lds[];          // 128 KB
    float* partA = lds;                     // cell2 partials
    float* partB = lds + 16384;             // cell1 partials

    const int tid  = threadIdx.x;
    const int w    = tid >> 6;
    const int lane = tid & 63;
    const int quad = lane >> 4;
    const int l16  = lane & 15;
    const int s    = w & 1;
    const int kq   = w >> 1;
    const int cg   = blockIdx.x & 63;
    const int mqh  = blockIdx.x >> 6;
    const int R0   = mqh * 32;
    const int J0   = cg * 16;
    const int rr   = tid >> 4;              // epilogue local row 0..31
    const int jj   = tid & 15;              // epilogue local col
    const int col  = J0 + jj;
    const int grow = R0 + rr;
    const size_t off = (size_t)grow * DIM + col;

    const int arow0 = R0 + l16;
    const int arow1 = R0 + 16 + l16;
    const int kb    = kq * 256 + quad * 8;
    const size_t aoff0 = (size_t)arow0 * DIM + kb;
    const size_t aoff1 = (size_t)arow1 * DIM + kb;

    unsigned* scd = sync + (mqh << 10);     // per-row-group 4KB barrier region

    __hip_bfloat16* hbf0  = hbase;
    __hip_bfloat16* hbf1  = hbase + BD;
    __hip_bfloat16* h1bf0 = hbase + 2 * BD;
    __hip_bfloat16* h1bf1 = hbase + 3 * BD;
    __hip_bfloat16* h2bf0 = hbase + 4 * BD;
    __hip_bfloat16* h2bf1 = hbase + 5 * BD;

    // ---- persistent weight fragments: W[n=j*4+g][k] ----
    bf16x8 breg[4][8];
    {
        const float* Wm = s ? Whh : Wih;
#pragma unroll
        for (int nt = 0; nt < 4; ++nt) {
            int n = nt * 16 + l16;
            const float* wp = Wm + (size_t)((n & 3) * DIM + J0 + (n >> 2)) * DIM + kb;
#pragma unroll
            for (int kc = 0; kc < 8; ++kc)
                breg[nt][kc] = pack_f32(*(const float4*)(wp + kc * 32),
                                        *(const float4*)(wp + kc * 32 + 4));
        }
    }

    // ---- persistent per-thread cell state ----
    float hc  = h0[col],  cc1 = c0[col];
    float hp  = hc,       cp  = cc1;        // layer-1 pre-state (cell2 pad fallback)
    float h2f = h02[col], c2f = c02[col];
    float bias[4];
#pragma unroll
    for (int g = 0; g < 4; ++g) bias[g] = bih[g * DIM + col] + bhh[g * DIM + col];

    // token registers, preloaded one phase ahead (x is read-only, cached)
    int ta0 = x[arow0], ta1 = x[arow1];     // gather rows for cell1 A-frags (s==0)
    int gxc = x[grow];                      // pad-mask token for MY row, step t
    int gxp = 0;

    st_dev_bf16(hbf1 + off, hc);            // parity 1 = state before step 0
    st_dev_bf16(h2bf1 + off, h2f);
    gsync(scd, cg);

#pragma unroll 1
    for (int t = 0; t <= SEQ; ++t) {
        bf16x8 afr1[2][8];
        if (t >= 1) {
            // ---- cell2(t-1) GEMM: s=0 -> h1(t-1)@Wih, s=1 -> h2(t-2)@Whh ----
            const __hip_bfloat16* Ab = (s == 0)
                ? (((t - 1) & 1) ? h1bf1 : h1bf0)
                : ((t & 1) ? h2bf1 : h2bf0);
            bf16x8 afr2[2][8];
            load_h_frags(afr2, Ab, aoff0, aoff1);
            f32x4 acc[2][4];
#pragma unroll
            for (int mt = 0; mt < 2; ++mt)
#pragma unroll
                for (int nt = 0; nt < 4; ++nt) acc[mt][nt] = (f32x4)(0.f);
            mfma_all(afr2, breg, acc);
            // issue cell1 operand loads now: the vmcnt drain at the next
            // __syncthreads covers this latency.
            if (t < SEQ) {
                if (s == 0)
                    load_emb_frags(afr1, emb + (size_t)ta0 * DIM + kb,
                                         emb + (size_t)ta1 * DIM + kb);
                else
                    load_h_frags(afr1, ((t + 1) & 1) ? hbf1 : hbf0, aoff0, aoff1);
            }
            write_part(partA, acc, w, quad, l16);
        } else {
            if (s == 0)
                load_emb_frags(afr1, emb + (size_t)ta0 * DIM + kb,
                                     emb + (size_t)ta1 * DIM + kb);
            else
                load_h_frags(afr1, hbf1, aoff0, aoff1);
        }
        __syncthreads();
        if (t >= 1) {
            // ---- epilogue cell2(t-1) ----
            float g4[4]; read_part(partA, rr, jj, g4);
            float gi = g4[0] + bias[0], gf = g4[1] + bias[1];
            float gg = g4[2] + bias[2], go = g4[3] + bias[3];
            float cn = sigf(gf) * c2f + sigf(gi) * tanhf(gg);
            float hn = sigf(go) * tanhf(cn);
            bool pad = (gxp == 0);
            h2f = pad ? hp : hn;            // pad fallback = layer-1 PRE-state
            c2f = pad ? cp : cn;
            st_row8((((t - 1) & 1) ? h2bf1 : h2bf0) + (off & ~(size_t)3), h2f, jj);
        }
        if (t < SEQ) {
            // ---- cell1(t) GEMM (operands already resident) ----
            f32x4 acc[2][4];
#pragma unroll
            for (int mt = 0; mt < 2; ++mt)
#pragma unroll
                for (int nt = 0; nt < 4; ++nt) acc[mt][nt] = (f32x4)(0.f);
            mfma_all(afr1, breg, acc);
            write_part(partB, acc, w, quad, l16);
            __syncthreads();
            // ---- epilogue cell1(t) ----
            float g4[4]; read_part(partB, rr, jj, g4);
            float gi = g4[0] + bias[0], gf = g4[1] + bias[1];
            float gg = g4[2] + bias[2], go = g4[3] + bias[3];
            float cn = sigf(gf) * cc1 + sigf(gi) * tanhf(gg);
            float hn = sigf(go) * tanhf(cn);
            bool pad = (gxc == 0);
            float hm = pad ? hc : hn;
            float cm = pad ? cc1 : cn;
            st_row8(((t & 1) ? h1bf1 : h1bf0) + (off & ~(size_t)3), hn, jj); // UNMASKED -> layer2
            st_row8(((t & 1) ? hbf1 : hbf0) + (off & ~(size_t)3), hm, jj);   // masked -> next cell1
            hp = hc; cp = cc1; hc = hm; cc1 = cm;
            gxp = gxc;
            int tn = (t + 1 < SEQ) ? t + 1 : t;                 // preload next tokens
            gxc = x[tn * BATCH + grow];
            ta0 = x[tn * BATCH + arow0];
            ta1 = x[tn * BATCH + arow1];
            gsync(scd, cg);
        }
    }

    out[0 * BD + off] = hc;
    out[1 * BD + off] = cc1;
    out[2 * BD + off] = h2f;
    out[3 * BD + off] = c2f;
}

__global__ void zero_sync_k(unsigned* sc) {
    sc[blockIdx.x * blockDim.x + threadIdx.x] = 0u;   // 4 domains x 1024 dwords
}

extern "C" void kernel_launch(void* const* d_in, const int* in_sizes, int n_in,
                              void* d_out, int out_size, void* d_ws, size_t ws_size,
                              hipStream_t stream) {
    (void)in_sizes; (void)n_in; (void)out_size; (void)ws_size;
    const int*   x    = (const int*)d_in[0];
    const float* emb  = (const float*)d_in[1];
    const float* Wih  = (const float*)d_in[2];
    const float* Whh  = (const float*)d_in[3];
    const float* bih  = (const float*)d_in[4];
    const float* bhh  = (const float*)d_in[5];
    const float* h0   = (const float*)d_in[6];
    const float* c0   = (const float*)d_in[7];
    const float* h02  = (const float*)d_in[8];
    const float* c02  = (const float*)d_in[9];

    unsigned* sync = (unsigned*)d_ws;
    __hip_bfloat16* hbase = (__hip_bfloat16*)((char*)d_ws + 16384);
    float* outp = (float*)d_out;

    static int attr_done = 0;
    if (!attr_done) {
        (void)hipFuncSetAttribute((const void*)lstm_persist,
                                  hipFuncAttributeMaxDynamicSharedMemorySize, LDS_BYTES);
        attr_done = 1;
    }

    zero_sync_k<<<8, 512, 0, stream>>>(sync);

    void* args[] = { (void*)&x, (void*)&emb, (void*)&Wih, (void*)&Whh,
                     (void*)&bih, (void*)&bhh, (void*)&h0, (void*)&c0,
                     (void*)&h02, (void*)&c02, (void*)&hbase, (void*)&sync,
                     (void*)&outp };
    hipError_t e = hipLaunchCooperativeKernel((const void*)lstm_persist,
                                              dim3(NBLK), dim3(512), args,
                                              (unsigned)LDS_BYTES, stream);
    if (e != hipSuccess) {
        // Fallback: plain launch. 128 KB LDS -> 1 block/CU, grid == CU count,
        // all 256 blocks co-resident; hand-rolled barrier remains safe.
        lstm_persist<<<NBLK, 512, LDS_BYTES, stream>>>(
            x, emb, Wih, Whh, bih, bhh, h0, c0, h02, c02, hbase, sync, outp);
    }
}

// Round 6
// 9807.835 us; speedup vs baseline: 2.9037x; 1.2138x over previous
//
#include <hip/hip_runtime.h>
#include <hip/hip_bf16.h>
#include <stdint.h>

#define SEQ   512
#define BATCH 128
#define DIM   1024
#define BD    (BATCH * DIM)
#define NBLK  256
#define LDS_BYTES 131072

typedef __bf16 bf16x8 __attribute__((ext_vector_type(8)));
typedef float  f32x4  __attribute__((ext_vector_type(4)));

__device__ __forceinline__ float sigf(float x) { return 1.0f / (1.0f + __expf(-x)); }
// branchless tanh: 1 - 2/(e^2x + 1); saturates correctly at +/-inf.
__device__ __forceinline__ float fast_tanh(float x) {
    float e = __expf(2.0f * x);
    return 1.0f - 2.0f / (e + 1.0f);
}

__device__ __forceinline__ bf16x8 pack_f32(float4 a, float4 b) {
    bf16x8 r;
    r[0] = (__bf16)a.x; r[1] = (__bf16)a.y; r[2] = (__bf16)a.z; r[3] = (__bf16)a.w;
    r[4] = (__bf16)b.x; r[5] = (__bf16)b.y; r[6] = (__bf16)b.z; r[7] = (__bf16)b.w;
    return r;
}
// Plain cached 16B load of 8 bf16 (h-state; cross-XCD visibility via the
// per-phase acquire fence in flag_wait).
__device__ __forceinline__ bf16x8 ld_b16x8(const __hip_bfloat16* p) {
    uint4 u = *reinterpret_cast<const uint4*>(p);
    return __builtin_bit_cast(bf16x8, u);
}
// Writer side: agent-scope relaxed (sc1 write-through to MALL), no cache
// maintenance instructions.
__device__ __forceinline__ void st_dev_bf16(__hip_bfloat16* p, float v) {
    unsigned short u = __builtin_bit_cast(unsigned short, (__bf16)v);
    __hip_atomic_store((unsigned short*)p, u, __ATOMIC_RELAXED, __HIP_MEMORY_SCOPE_AGENT);
}
// 4 neighboring cols gathered by shuffle -> one 8B agent store.
__device__ __forceinline__ void st_row8(__hip_bfloat16* p, float v, int jj) {
    float v1 = __shfl_down(v, 1);
    float v2 = __shfl_down(v, 2);
    float v3 = __shfl_down(v, 3);
    if ((jj & 3) == 0) {
        union { unsigned short s[4]; unsigned long long u; } q;
        q.s[0] = __builtin_bit_cast(unsigned short, (__bf16)v);
        q.s[1] = __builtin_bit_cast(unsigned short, (__bf16)v1);
        q.s[2] = __builtin_bit_cast(unsigned short, (__bf16)v2);
        q.s[3] = __builtin_bit_cast(unsigned short, (__bf16)v3);
        __hip_atomic_store((unsigned long long*)p, q.u, __ATOMIC_RELAXED,
                           __HIP_MEMORY_SCOPE_AGENT);
    }
}
__device__ __forceinline__ unsigned ld_sc(const unsigned* p) {
    return __hip_atomic_load(p, __ATOMIC_RELAXED, __HIP_MEMORY_SCOPE_AGENT);
}
__device__ __forceinline__ void st_sc(unsigned* p, unsigned v) {
    __hip_atomic_store(p, v, __ATOMIC_RELAXED, __HIP_MEMORY_SCOPE_AGENT);
}

// Flag-based domain sync: no RMWs, no resets. Producer b stores flag[b]=t+2
// (monotonic phase count) AFTER its h-stores drained; consumers' wave 0 polls
// the domain's 64 flags (lane b -> flag[b], 16B stride) until all >= thr.
// One MALL store + ~one poll round of release latency; the acquire fence
// (L1+L2 inv, once per phase) makes peers' MALL-written h visible to the
// plain cached loads. R2-R5 lesson: counter RMWs to one line serialize at
// MALL and acquire-polls storm the caches -- both avoided here.
__device__ __forceinline__ void flag_wait(unsigned* scd, unsigned thr) {
    if (threadIdx.x < 64) {
        for (;;) {
            unsigned v = ld_sc(scd + threadIdx.x * 4);
            if (__all((int)(v >= thr))) break;
            __builtin_amdgcn_s_sleep(2);
        }
    }
    if (threadIdx.x == 0)
        __builtin_amdgcn_fence(__ATOMIC_ACQUIRE, "agent");
    __syncthreads();
}

// All 16 A-fragment loads issued up-front: one MALL exposure per operand set.
__device__ __forceinline__ void load_h_frags(bf16x8 (&afr)[2][8],
    const __hip_bfloat16* Ab, size_t aoff0, size_t aoff1)
{
#pragma unroll
    for (int kc = 0; kc < 8; ++kc) {
        afr[0][kc] = ld_b16x8(Ab + aoff0 + kc * 32);
        afr[1][kc] = ld_b16x8(Ab + aoff1 + kc * 32);
    }
}

// ebuf: 32 rows x 1024 bf16 (64 KB), row stride 2048B, 16B blocks
// XOR-swizzled by (row&7) so the wave's stride-2048 fragment reads spread
// across all bank groups (2 rows/slot = free).
__device__ __forceinline__ void ebuf_read_frags(bf16x8 (&afr)[2][8],
    const char* ebuf, int kq, int quad, int l16)
{
#pragma unroll
    for (int mt = 0; mt < 2; ++mt) {
        int r = mt * 16 + l16;
        const char* base = ebuf + r * 2048;
        int sw = r & 7;
#pragma unroll
        for (int kc = 0; kc < 8; ++kc) {
            int cb = kq * 32 + kc * 4 + quad;
            afr[mt][kc] = *(const bf16x8*)(base + ((cb ^ sw) * 16));
        }
    }
}
// Fill ebuf for the next step: thread -> row er=tid>>4, 64 cols at ecb*8.
// Runs entirely in the post-flag slack window (overlaps peers' polling).
__device__ __forceinline__ void ebuf_fill(char* ebuf, int er, int ecb, const float* ep)
{
    char* base = ebuf + er * 2048;
    int sw = er & 7;
#pragma unroll
    for (int i = 0; i < 8; ++i) {
        float4 a = *(const float4*)(ep + i * 8);
        float4 b = *(const float4*)(ep + i * 8 + 4);
        *(bf16x8*)(base + (((ecb + i) ^ sw) * 16)) = pack_f32(a, b);
    }
}

__device__ __forceinline__ void mfma_all(const bf16x8 (&afr)[2][8],
    const bf16x8 (&breg)[4][8], f32x4 (&acc)[2][4])
{
#pragma unroll
    for (int kc = 0; kc < 8; ++kc)
#pragma unroll
        for (int mt = 0; mt < 2; ++mt)
#pragma unroll
            for (int nt = 0; nt < 4; ++nt)
                acc[mt][nt] = __builtin_amdgcn_mfma_f32_16x16x32_bf16(
                    afr[mt][kc], breg[nt][kc], acc[mt][nt], 0, 0, 0);
}

// Partials part[w][n=64][m=32] f32, m-index XOR-swizzled by
// a(n) = ((n>>2)&7) ^ ((n&3)<<1): b128 writes spread over all 8 bank groups,
// scalar epilogue reads cover 32 banks at 2 lanes/bank.
__device__ __forceinline__ void write_part(float* part, const f32x4 (&acc)[2][4],
    int w, int quad, int l16)
{
#pragma unroll
    for (int mt = 0; mt < 2; ++mt)
#pragma unroll
        for (int nt = 0; nt < 4; ++nt) {
            int n  = nt * 16 + l16;
            int a  = ((n >> 2) & 7) ^ ((n & 3) << 1);
            int dw = w * 2048 + n * 32 + ((mt * 16 + quad * 4) ^ (a << 2));
            *(f32x4*)(part + dw) = acc[mt][nt];
        }
}
__device__ __forceinline__ void read_part(const float* part, int rr, int jj, float (&g4)[4])
{
    g4[0] = g4[1] = g4[2] = g4[3] = 0.f;
#pragma unroll
    for (int wv = 0; wv < 8; ++wv)
#pragma unroll
        for (int g = 0; g < 4; ++g) {
            int a = ((jj & 7) ^ (g << 1));
            g4[g] += part[wv * 2048 + (jj * 4 + g) * 32 + (rr ^ (a << 2))];
        }
}

// Block = 32 batch rows x 16 hidden cols. Wave (s,kq). Weights persistent in
// regs. Per phase: cell2 GEMM (h loads post-fence) -> cell1 operand fetch
// (s=0: LDS ebuf, s=1: global prefetch) -> sync1 -> epi2 -> cell1 GEMM ->
// sync -> epi1 -> drain-sync -> flag store -> emb(t+1) -> ebuf -> poll.
__global__ __launch_bounds__(512, 2) void lstm_persist(
    const int* __restrict__ x, const float* __restrict__ emb,
    const float* __restrict__ Wih, const float* __restrict__ Whh,
    const float* __restrict__ bih, const float* __restrict__ bhh,
    const float* __restrict__ h0, const float* __restrict__ c0,
    const float* __restrict__ h02, const float* __restrict__ c02,
    __hip_bfloat16* __restrict__ hbase, unsigned* __restrict__ sync,
    float* __restrict__ out)
{
    extern __shared__ float lds[];          // 128 KB
    float* partA = lds;                     // cell2 partials [0,64K)
    float* partB = lds + 16384;             // cell1 partials [64K,128K)
    char*  ebuf  = (char*)(lds + 16384);    // ALIASES partB: ebuf(t) is fully
                                            // consumed by cell1's ds_reads
                                            // (pre-sync1) before write_part(partB)

    const int tid  = threadIdx.x;
    const int w    = tid >> 6;
    const int lane = tid & 63;
    const int quad = lane >> 4;
    const int l16  = lane & 15;
    const int s    = w & 1;
    const int kq   = w >> 1;
    const int cg   = blockIdx.x & 63;
    const int mqh  = blockIdx.x >> 6;
    const int R0   = mqh * 32;
    const int J0   = cg * 16;
    const int rr   = tid >> 4;              // epilogue local row 0..31
    const int jj   = tid & 15;              // epilogue local col
    const int col  = J0 + jj;
    const int grow = R0 + rr;
    const size_t off = (size_t)grow * DIM + col;
    const int er   = tid >> 4;              // ebuf row (== rr)
    const int ecb  = (tid & 15) * 8;        // ebuf 16B-block base

    const int arow0 = R0 + l16;
    const int arow1 = R0 + 16 + l16;
    const int kb    = kq * 256 + quad * 8;
    const size_t aoff0 = (size_t)arow0 * DIM + kb;
    const size_t aoff1 = (size_t)arow1 * DIM + kb;

    unsigned* scd = sync + (mqh << 10);     // per-row-group flag region

    __hip_bfloat16* hbf0  = hbase;
    __hip_bfloat16* hbf1  = hbase + BD;
    __hip_bfloat16* h1bf0 = hbase + 2 * BD;
    __hip_bfloat16* h1bf1 = hbase + 3 * BD;
    __hip_bfloat16* h2bf0 = hbase + 4 * BD;
    __hip_bfloat16* h2bf1 = hbase + 5 * BD;

    // ---- persistent weight fragments: W[n=j*4+g][k] ----
    bf16x8 breg[4][8];
    {
        const float* Wm = s ? Whh : Wih;
#pragma unroll
        for (int nt = 0; nt < 4; ++nt) {
            int n = nt * 16 + l16;
            const float* wp = Wm + (size_t)((n & 3) * DIM + J0 + (n >> 2)) * DIM + kb;
#pragma unroll
            for (int kc = 0; kc < 8; ++kc)
                breg[nt][kc] = pack_f32(*(const float4*)(wp + kc * 32),
                                        *(const float4*)(wp + kc * 32 + 4));
        }
    }

    // ---- persistent per-thread cell state ----
    float hc  = h0[col],  cc1 = c0[col];
    float hp  = hc,       cp  = cc1;        // layer-1 pre-state (cell2 pad fallback)
    float h2f = h02[col], c2f = c02[col];
    float bias[4];
#pragma unroll
    for (int g = 0; g < 4; ++g) bias[g] = bih[g * DIM + col] + bhh[g * DIM + col];

    int gxc = x[grow];                      // pad token for MY row, step t
    int gxp = 0;

    st_dev_bf16(hbf1 + off, hc);            // parity 1 = state before step 0
    st_dev_bf16(h2bf1 + off, h2f);
    {   // ebuf for t=0
        int tok = x[R0 + er];
        ebuf_fill(ebuf, er, ecb, emb + (size_t)tok * DIM + ecb * 8);
    }
    __syncthreads();                        // drain init stores + ebuf writes
    if (tid == 0) st_sc(scd + cg * 4, 1u);

#pragma unroll 1
    for (int t = 0; t <= SEQ; ++t) {
        flag_wait(scd, (unsigned)(t + 1));
        bf16x8 afr[2][8];
        if (t >= 1) {
            // ---- cell2(t-1): s=0 -> h1(t-1)@Wih, s=1 -> h2(t-2)@Whh ----
            const __hip_bfloat16* Ab = (s == 0)
                ? (((t - 1) & 1) ? h1bf1 : h1bf0)
                : ((t & 1) ? h2bf1 : h2bf0);
            load_h_frags(afr, Ab, aoff0, aoff1);
            f32x4 acc[2][4];
#pragma unroll
            for (int mt = 0; mt < 2; ++mt)
#pragma unroll
                for (int nt = 0; nt < 4; ++nt) acc[mt][nt] = (f32x4)(0.f);
            mfma_all(afr, breg, acc);
            // cell1 operands (reuse afr): s=1 global prefetch drains at sync1;
            // s=0 reads ebuf (stable since last phase) -- done before sync1 so
            // sync1 also guards the partB/ebuf alias.
            if (t < SEQ) {
                if (s == 1) load_h_frags(afr, ((t + 1) & 1) ? hbf1 : hbf0, aoff0, aoff1);
                else        ebuf_read_frags(afr, ebuf, kq, quad, l16);
            }
            write_part(partA, acc, w, quad, l16);
            __syncthreads();                // sync1
            {   // ---- epilogue cell2(t-1) ----
                float g4[4]; read_part(partA, rr, jj, g4);
                float gi = g4[0] + bias[0], gf = g4[1] + bias[1];
                float gg = g4[2] + bias[2], go = g4[3] + bias[3];
                float cn = sigf(gf) * c2f + sigf(gi) * fast_tanh(gg);
                float hn = sigf(go) * fast_tanh(cn);
                bool pad = (gxp == 0);
                h2f = pad ? hp : hn;        // pad fallback = layer-1 PRE-state
                c2f = pad ? cp : cn;
                st_row8((((t - 1) & 1) ? h2bf1 : h2bf0) + (off & ~(size_t)3), h2f, jj);
            }
        } else {
            if (s == 1) load_h_frags(afr, hbf1, aoff0, aoff1);
            else        ebuf_read_frags(afr, ebuf, kq, quad, l16);
            __syncthreads();                // ebuf reads done before partB write
        }
        if (t < SEQ) {
            // ---- cell1(t) GEMM (operands resident) ----
            f32x4 acc[2][4];
#pragma unroll
            for (int mt = 0; mt < 2; ++mt)
#pragma unroll
                for (int nt = 0; nt < 4; ++nt) acc[mt][nt] = (f32x4)(0.f);
            mfma_all(afr, breg, acc);
            write_part(partB, acc, w, quad, l16);
            __syncthreads();                // partB visible
            {   // ---- epilogue cell1(t) ----
                float g4[4]; read_part(partB, rr, jj, g4);
                float gi = g4[0] + bias[0], gf = g4[1] + bias[1];
                float gg = g4[2] + bias[2], go = g4[3] + bias[3];
                float cn = sigf(gf) * cc1 + sigf(gi) * fast_tanh(gg);
                float hn = sigf(go) * fast_tanh(cn);
                bool pad = (gxc == 0);
                float hm = pad ? hc : hn;
                float cm = pad ? cc1 : cn;
                st_row8(((t & 1) ? h1bf1 : h1bf0) + (off & ~(size_t)3), hn, jj);
                st_row8(((t & 1) ? hbf1 : hbf0) + (off & ~(size_t)3), hm, jj);
                hp = hc; cp = cc1; hc = hm; cc1 = cm;
                gxp = gxc;
            }
            __syncthreads();                // drain h stores + partB reads done
            if (tid == 0) st_sc(scd + cg * 4, (unsigned)(t + 2));  // release peers
            // ---- slack work (overlaps peers' polling): tokens + ebuf(t+1) ----
            if (t + 1 < SEQ) {
                int tn = t + 1;
                gxc = x[tn * BATCH + grow];
                int tok = x[tn * BATCH + R0 + er];
                ebuf_fill(ebuf, er, ecb, emb + (size_t)tok * DIM + ecb * 8);
                // ebuf writes complete before next phase's reads: the
                // flag_wait barrier at loop top orders LDS within the block.
            }
        }
    }

    out[0 * BD + off] = hc;
    out[1 * BD + off] = cc1;
    out[2 * BD + off] = h2f;
    out[3 * BD + off] = c2f;
}

__global__ void zero_sync_k(unsigned* sc) {
    sc[blockIdx.x * blockDim.x + threadIdx.x] = 0u;   // 4 domains x 1024 dwords
}

extern "C" void kernel_launch(void* const* d_in, const int* in_sizes, int n_in,
                              void* d_out, int out_size, void* d_ws, size_t ws_size,
                              hipStream_t stream) {
    (void)in_sizes; (void)n_in; (void)out_size; (void)ws_size;
    const int*   x    = (const int*)d_in[0];
    const float* emb  = (const float*)d_in[1];
    const float* Wih  = (const float*)d_in[2];
    const float* Whh  = (const float*)d_in[3];
    const float* bih  = (const float*)d_in[4];
    const float* bhh  = (const float*)d_in[5];
    const float* h0   = (const float*)d_in[6];
    const float* c0   = (const float*)d_in[7];
    const float* h02  = (const float*)d_in[8];
    const float* c02  = (const float*)d_in[9];

    unsigned* sync = (unsigned*)d_ws;
    __hip_bfloat16* hbase = (__hip_bfloat16*)((char*)d_ws + 16384);
    float* outp = (float*)d_out;

    static int attr_done = 0;
    if (!attr_done) {
        (void)hipFuncSetAttribute((const void*)lstm_persist,
                                  hipFuncAttributeMaxDynamicSharedMemorySize, LDS_BYTES);
        attr_done = 1;
    }

    zero_sync_k<<<8, 512, 0, stream>>>(sync);

    void* args[] = { (void*)&x, (void*)&emb, (void*)&Wih, (void*)&Whh,
                     (void*)&bih, (void*)&bhh, (void*)&h0, (void*)&c0,
                     (void*)&h02, (void*)&c02, (void*)&hbase, (void*)&sync,
                     (void*)&outp };
    hipError_t e = hipLaunchCooperativeKernel((const void*)lstm_persist,
                                              dim3(NBLK), dim3(512), args,
                                              (unsigned)LDS_BYTES, stream);
    if (e != hipSuccess) {
        // Fallback: plain launch. 128 KB LDS -> 1 block/CU, grid == CU count,
        // all 256 blocks co-resident; flag sync remains safe.
        lstm_persist<<<NBLK, 512, LDS_BYTES, stream>>>(
            x, emb, Wih, Whh, bih, bhh, h0, c0, h02, c02, hbase, sync, outp);
    }
}